// Round 14
// baseline (351.391 us; speedup 1.0000x reference)
//
#include <hip/hip_runtime.h>

// AFNO spectral attention, MI355X — r12 spectral pipeline + 4-buffer 1-barrier GEMM.
// GEMM ledger: single-buf 128^2=163; 2-ph drain0=194; no-LDS=316; 256x128=207;
// 2-ph counted vmcnt(8)=149 (r13, T4 validated). This round: T3 deep pipeline —
// 4 LDS buffers (128KB), stage-lead 2, ONE raw barrier/iter, vmcnt(16):
//   write-safety: STAGE@kt targets buf read @kt-2, separated by BAR(kt-1);
//   visibility: reads follow BAR(kt) which follows every wave's vmcnt(16).
// Cover = 2 iterations (~1600cy > 900cy HBM). Address math byte-identical to r13.

#define B_ 16
#define H_ 64
#define W_ 64
#define C_ 768
#define NB_ 8
#define BS_ 96
#define MODES_ 8
#define HW_ 4096
#define SPA 776   // sA bf16 row stride: 1552 B/row -> 2-way LDS aliasing (free)

typedef float f32x4 __attribute__((ext_vector_type(4)));
typedef __bf16 bf16x8 __attribute__((ext_vector_type(8)));

__device__ __forceinline__ float bf2f(unsigned short u){
  unsigned int v = ((unsigned int)u) << 16;
  return __builtin_bit_cast(float, v);
}
__device__ __forceinline__ unsigned short f2bf(float f){
  unsigned int v = __builtin_bit_cast(unsigned int, f);
  v = v + 0x7FFFu + ((v >> 16) & 1u);   // RNE (finite data)
  return (unsigned short)(v >> 16);
}

// merged: blocks [0,2304) convert W_out -> Wb bf16; blocks [2304,2312) build Wp.
__global__ __launch_bounds__(256) void k_cvt_prep(const float* __restrict__ W_out,
    unsigned short* __restrict__ Wb, const float* __restrict__ bW,
    const float* __restrict__ gates, unsigned short* __restrict__ Wp){
  const int bid = blockIdx.x, tid = threadIdx.x;
  if (bid < 2304){
    int i = bid * 256 + tid;
    Wb[i] = f2bf(W_out[i]);           // n = C_*NB_*BS_ = 589824 = 2304*256 exactly
  } else {
    const int n = bid - 2304;
    const float g = 1.f / (1.f + expf(-gates[n]));
    for (int i = tid; i < BS_ * BS_; i += 256){
      int d = i / BS_, c = i - d * BS_;
      Wp[(size_t)n * BS_ * BS_ + i] = f2bf(g * bW[(size_t)n * BS_ * BS_ + c * BS_ + d]);
    }
  }
}

// ---- forward W-DFT (r1/r5/r6 verbatim)
__global__ __launch_bounds__(256) void k_fwd_w(const float* __restrict__ x, float* __restrict__ S){
  __shared__ float tab[MODES_][W_][2]; // cos, -sin
  const int tid = threadIdx.x;
  for (int i = tid; i < MODES_ * W_; i += 256){
    int m = i >> 6, w = i & 63;
    float s, c; sincospif((float)((m * w) & 63) * (1.f / 32.f), &s, &c);
    tab[m][w][0] = c; tab[m][w][1] = -s;
  }
  __syncthreads();
  const int b = blockIdx.x >> 6, h = blockIdx.x & 63;
  const float* xr = x + ((size_t)b * HW_ + (size_t)h * W_) * C_;
  float ar[MODES_][3], ai[MODES_][3];
  #pragma unroll
  for (int m = 0; m < MODES_; ++m){
    #pragma unroll
    for (int j = 0; j < 3; ++j){ ar[m][j] = 0.f; ai[m][j] = 0.f; }
  }
  for (int w = 0; w < W_; ++w){
    float xv0 = xr[(size_t)w * C_ + tid];
    float xv1 = xr[(size_t)w * C_ + tid + 256];
    float xv2 = xr[(size_t)w * C_ + tid + 512];
    #pragma unroll
    for (int m = 0; m < MODES_; ++m){
      float c = tab[m][w][0], s = tab[m][w][1];
      ar[m][0] += xv0 * c; ai[m][0] += xv0 * s;
      ar[m][1] += xv1 * c; ai[m][1] += xv1 * s;
      ar[m][2] += xv2 * c; ai[m][2] += xv2 * s;
    }
  }
  float* Sp = S + ((size_t)(b * H_ + h) * (MODES_ * 2)) * C_;
  #pragma unroll
  for (int m = 0; m < MODES_; ++m){
    #pragma unroll
    for (int j = 0; j < 3; ++j){
      Sp[(size_t)(m * 2 + 0) * C_ + tid + j * 256] = ar[m][j];
      Sp[(size_t)(m * 2 + 1) * C_ + tid + j * 256] = ai[m][j];
    }
  }
}

// ---- MFMA block mixing, in place on S (r6 verbatim)
__global__ __launch_bounds__(256) void k_mix2(float* __restrict__ T,
    const unsigned short* __restrict__ Wp, const float* __restrict__ bb,
    const float* __restrict__ gates){
  __shared__ __align__(16) unsigned short sA[16 * SPA];
  const int tid = threadIdx.x;
  float* Tg = T + (size_t)blockIdx.x * 16 * C_;
  #pragma unroll
  for (int r = 0; r < 16; ++r){
    #pragma unroll
    for (int j = 0; j < 3; ++j){
      const int c = tid + 256 * j;
      sA[r * SPA + c] = f2bf(Tg[(size_t)r * C_ + c]);
    }
  }
  __syncthreads();
  const int wv = tid >> 6, ln = tid & 63;
  f32x4 acc[2][6];
  #pragma unroll
  for (int i = 0; i < 2; ++i)
    #pragma unroll
    for (int j = 0; j < 6; ++j) acc[i][j] = {0.f, 0.f, 0.f, 0.f};
  #pragma unroll
  for (int nn = 0; nn < 2; ++nn){
    const int n = wv * 2 + nn, col0 = n * BS_;
    #pragma unroll
    for (int ks = 0; ks < 3; ++ks){
      bf16x8 af = *(const bf16x8*)(sA + (ln & 15) * SPA + col0 + ks * 32 + (ln >> 4) * 8);
      #pragma unroll
      for (int ct = 0; ct < 6; ++ct){
        const unsigned short* bp = Wp + ((size_t)n * BS_ + ct * 16 + (ln & 15)) * BS_
                                      + ks * 32 + (ln >> 4) * 8;
        bf16x8 bf = *(const bf16x8*)bp;
        acc[nn][ct] = __builtin_amdgcn_mfma_f32_16x16x32_bf16(af, bf, acc[nn][ct], 0, 0, 0);
      }
    }
  }
  #pragma unroll
  for (int nn = 0; nn < 2; ++nn){
    const int n = wv * 2 + nn;
    const float g = 1.f / (1.f + expf(-gates[n]));
    #pragma unroll
    for (int ct = 0; ct < 6; ++ct){
      const int dcol = ct * 16 + (ln & 15);
      const int col = n * BS_ + dcol;
      const float gb = g * bb[n * BS_ + dcol];
      #pragma unroll
      for (int j = 0; j < 4; ++j){
        const int row = (ln >> 4) * 4 + j;               // C/D: col=lane&15, row=(lane>>4)*4+j
        const float wgt = (row < 2 ? 1.f : 2.f) * (1.f / 64.f);
        const size_t o = (size_t)row * C_ + col;
        Tg[o] = (acc[nn][ct][j] + gb - Tg[o]) * wgt;
      }
    }
  }
}

// ---- inverse W-DFT + residual add, emit x_out as bf16 (r1/r5/r6 verbatim)
__global__ __launch_bounds__(256) void k_inv_w(const float* __restrict__ Z, const float* __restrict__ x,
                                               unsigned short* __restrict__ xo){
  __shared__ float tab[W_][MODES_][2]; // cos, sin
  const int tid = threadIdx.x;
  for (int i = tid; i < W_ * MODES_; i += 256){
    int w = i >> 3, m = i & 7;
    float s, c; sincospif((float)((w * m) & 63) * (1.f / 32.f), &s, &c);
    tab[w][m][0] = c; tab[w][m][1] = s;
  }
  __syncthreads();
  const int b = blockIdx.x >> 6, h = blockIdx.x & 63;
  const float* Zp = Z + ((size_t)(b * H_ + h) * 16) * C_;
  float zr[MODES_][3], zi[MODES_][3];
  #pragma unroll
  for (int m = 0; m < MODES_; ++m){
    #pragma unroll
    for (int j = 0; j < 3; ++j){
      zr[m][j] = Zp[(size_t)(m * 2 + 0) * C_ + tid + j * 256];
      zi[m][j] = Zp[(size_t)(m * 2 + 1) * C_ + tid + j * 256];
    }
  }
  const float* xr = x + ((size_t)b * HW_ + (size_t)h * W_) * C_;
  unsigned short* xop = xo + ((size_t)b * HW_ + (size_t)h * W_) * C_;
  for (int w = 0; w < W_; ++w){
    float y0 = 0.f, y1 = 0.f, y2 = 0.f;
    #pragma unroll
    for (int m = 0; m < MODES_; ++m){
      float cw = tab[w][m][0], sw = tab[w][m][1];
      y0 += zr[m][0] * cw - zi[m][0] * sw;
      y1 += zr[m][1] * cw - zi[m][1] * sw;
      y2 += zr[m][2] * cw - zi[m][2] * sw;
    }
    size_t o = (size_t)w * C_;
    xop[o + tid]       = f2bf(xr[o + tid] + y0);
    xop[o + tid + 256] = f2bf(xr[o + tid + 256] + y1);
    xop[o + tid + 512] = f2bf(xr[o + tid + 512] + y2);
  }
}

// ---- projection GEMM: 4-buffer deep pipeline, counted vmcnt(16), 1 barrier/iter.
__device__ __forceinline__ void async16(const void* g, const void* l){
  __builtin_amdgcn_global_load_lds((__attribute__((address_space(1))) void*)g,
                                   (__attribute__((address_space(3))) void*)l, 16, 0, 0);
}

__global__ __launch_bounds__(256) void k_gemm(const unsigned short* __restrict__ xo,
    const unsigned short* __restrict__ Wb, const float* __restrict__ b_out,
    const float* __restrict__ rescale, float* __restrict__ out){
  __shared__ __align__(16) unsigned short lA[4][128 * 64];   // 4 x 16 KB
  __shared__ __align__(16) unsigned short lB[4][128 * 64];   // 4 x 16 KB  (128 KB total)
  const int tid = threadIdx.x;
  const int wv = tid >> 6, ln = tid & 63;
  const int wg = (blockIdx.x & 7) * 384 + (blockIdx.x >> 3);   // XCD-aware bijective swizzle
  const int mt = wg / 6, nt = wg % 6;
  const int mbase = mt * 128, nbase = nt * 128;
  f32x4 acc[4][4];
  #pragma unroll
  for (int i = 0; i < 4; ++i)
    #pragma unroll
    for (int j = 0; j < 4; ++j) acc[i][j] = {0.f, 0.f, 0.f, 0.f};
  const int srow = ln >> 3;
  const int kb_lin = (ln & 7) << 4;

#define STAGE(pp, kt_) {                                                    \
    const int k0_ = (kt_) * 64;                                             \
    _Pragma("unroll")                                                       \
    for (int i_ = 0; i_ < 4; ++i_){                                         \
      const int ch_ = i_ * 4 + wv;                                          \
      const int row_ = ch_ * 8 + srow;                                      \
      const int kby_ = kb_lin ^ ((row_ & 7) << 4);                          \
      async16(xo + (size_t)(mbase + row_) * C_ + k0_ + (kby_ >> 1),         \
              ((const char*)lA[pp]) + ch_ * 1024);                          \
      async16(Wb + (size_t)(nbase + row_) * C_ + k0_ + (kby_ >> 1),         \
              ((const char*)lB[pp]) + ch_ * 1024);                          \
    } }
  // 8 loads/wave per STAGE, in-order vmcnt. Stage-lead 2: buffer kt is waited
  // two iterations after issue (cover ~1600cy). One barrier per iteration:
  //   STAGE@kt -> buf (kt+2)&3, last read @kt-2, separated by BAR(kt-1);
  //   reads(kt) follow BAR(kt), reached by each wave only after its vmcnt(16).
  STAGE(0, 0);
  STAGE(1, 1);
  #pragma unroll
  for (int kt = 0; kt < 12; ++kt){
    const int p = kt & 3;
    if (kt + 2 < 12) STAGE((kt + 2) & 3, kt + 2);
    if (kt < 10)       asm volatile("s_waitcnt vmcnt(16)" ::: "memory");
    else if (kt == 10) asm volatile("s_waitcnt vmcnt(8)"  ::: "memory");
    else               asm volatile("s_waitcnt vmcnt(0)"  ::: "memory");
    __builtin_amdgcn_s_barrier();
    __builtin_amdgcn_sched_barrier(0);
    const int wr = (wv >> 1) * 64, wc = (wv & 1) * 64;
    #pragma unroll
    for (int kk = 0; kk < 2; ++kk){
      bf16x8 af[4], bg[4];
      #pragma unroll
      for (int mi = 0; mi < 4; ++mi){
        const int row = wr + mi * 16 + (ln & 15);
        int off = (row << 7) + (kk << 6) + ((ln >> 4) << 4);
        off ^= (row & 7) << 4;                       // swizzled read (r13-validated)
        af[mi] = *(const bf16x8*)(((const char*)lA[p]) + off);
      }
      #pragma unroll
      for (int ni = 0; ni < 4; ++ni){
        const int row = wc + ni * 16 + (ln & 15);
        int off = (row << 7) + (kk << 6) + ((ln >> 4) << 4);
        off ^= (row & 7) << 4;
        bg[ni] = *(const bf16x8*)(((const char*)lB[p]) + off);
      }
      #pragma unroll
      for (int mi = 0; mi < 4; ++mi){
        #pragma unroll
        for (int ni = 0; ni < 4; ++ni)
          acc[mi][ni] = __builtin_amdgcn_mfma_f32_16x16x32_bf16(af[mi], bg[ni], acc[mi][ni], 0, 0, 0);
      }
    }
    __builtin_amdgcn_sched_barrier(0);
  }
#undef STAGE
  const float rs = *rescale;
  const int wr = (wv >> 1) * 64, wc = (wv & 1) * 64;
  #pragma unroll
  for (int mi = 0; mi < 4; ++mi){
    const int r0 = mbase + wr + mi * 16 + ((ln >> 4) << 2);
    #pragma unroll
    for (int ni = 0; ni < 4; ++ni){
      const int cidx = nbase + wc + ni * 16 + (ln & 15);
      const float bo = rs * b_out[cidx];
      #pragma unroll
      for (int j = 0; j < 4; ++j){
        const size_t o = (size_t)(r0 + j) * C_ + cidx;
        out[o] = bf2f(xo[o]) + rs * acc[mi][ni][j] + bo;  // C/D: col=lane&15, row=(lane>>4)*4+j
      }
    }
  }
}

extern "C" void kernel_launch(void* const* d_in, const int* in_sizes, int n_in,
                              void* d_out, int out_size, void* d_ws, size_t ws_size,
                              hipStream_t stream){
  const float* x       = (const float*)d_in[0];
  const float* bW      = (const float*)d_in[1];
  const float* bb      = (const float*)d_in[2];
  const float* gates   = (const float*)d_in[3];
  const float* W_out   = (const float*)d_in[4];
  const float* b_out   = (const float*)d_in[5];
  const float* rescale = (const float*)d_in[6];
  float* out = (float*)d_out;
  char* ws = (char*)d_ws;
  // ws layout (bytes): S 50331648 | xo bf16 100663296 | Wb bf16 1179648 | Wp bf16 147456
  float* S = (float*)(ws);
  unsigned short* xo = (unsigned short*)(ws + 50331648);
  unsigned short* Wb = (unsigned short*)(ws + 50331648 + 100663296);
  unsigned short* Wp = (unsigned short*)(ws + 50331648 + 100663296 + 1179648);

  k_cvt_prep<<<2312, 256, 0, stream>>>(W_out, Wb, bW, gates, Wp);
  k_fwd_w<<<B_ * H_, 256, 0, stream>>>(x, S);
  k_mix2<<<B_ * H_, 256, 0, stream>>>(S, Wp, bb, gates);   // MFMA mix, h-domain, in place
  k_inv_w<<<B_ * H_, 256, 0, stream>>>(S, x, xo);
  k_gemm<<<(HW_ * B_ / 128) * (C_ / 128), 256, 0, stream>>>(xo, Wb, b_out, rescale, out);
}

// Round 15
// 341.851 us; speedup vs baseline: 1.0279x; 1.0279x over previous
//
#include <hip/hip_runtime.h>

// AFNO spectral attention, MI355X — FINAL: r13 best-validated configuration.
// Algebra: block-diag channel mix is frequency-uniform -> commutes with the
// H-DFT pair -> H-transform eliminated (validated r5). Mix via MFMA (r6).
// GEMM: 128^2 tile, 2-buffer double-buffering with COUNTED vmcnt(8) + raw
// s_barrier (T4): next tile's 8 global_load_lds stay in flight across the
// barrier; __syncthreads' implicit vmcnt(0) drain would defeat it (r9: 194us).
// Ledger: single-buf=163, 2ph-drain0=194, no-LDS=316, 256x128=207,
// 2ph-counted=149 (BEST), 4buf-1bar=164 (1 block/CU kills co-residency).

#define B_ 16
#define H_ 64
#define W_ 64
#define C_ 768
#define NB_ 8
#define BS_ 96
#define MODES_ 8
#define HW_ 4096
#define SPA 776   // sA bf16 row stride: 1552 B/row -> 2-way LDS aliasing (free)

typedef float f32x4 __attribute__((ext_vector_type(4)));
typedef __bf16 bf16x8 __attribute__((ext_vector_type(8)));

__device__ __forceinline__ float bf2f(unsigned short u){
  unsigned int v = ((unsigned int)u) << 16;
  return __builtin_bit_cast(float, v);
}
__device__ __forceinline__ unsigned short f2bf(float f){
  unsigned int v = __builtin_bit_cast(unsigned int, f);
  v = v + 0x7FFFu + ((v >> 16) & 1u);   // RNE (finite data)
  return (unsigned short)(v >> 16);
}

// merged: blocks [0,2304) convert W_out -> Wb bf16; blocks [2304,2312) build Wp.
__global__ __launch_bounds__(256) void k_cvt_prep(const float* __restrict__ W_out,
    unsigned short* __restrict__ Wb, const float* __restrict__ bW,
    const float* __restrict__ gates, unsigned short* __restrict__ Wp){
  const int bid = blockIdx.x, tid = threadIdx.x;
  if (bid < 2304){
    int i = bid * 256 + tid;
    Wb[i] = f2bf(W_out[i]);           // n = C_*NB_*BS_ = 589824 = 2304*256 exactly
  } else {
    const int n = bid - 2304;
    const float g = 1.f / (1.f + expf(-gates[n]));
    for (int i = tid; i < BS_ * BS_; i += 256){
      int d = i / BS_, c = i - d * BS_;
      Wp[(size_t)n * BS_ * BS_ + i] = f2bf(g * bW[(size_t)n * BS_ * BS_ + c * BS_ + d]);
    }
  }
}

// ---- forward W-DFT (r1/r5/r6 verbatim)
__global__ __launch_bounds__(256) void k_fwd_w(const float* __restrict__ x, float* __restrict__ S){
  __shared__ float tab[MODES_][W_][2]; // cos, -sin
  const int tid = threadIdx.x;
  for (int i = tid; i < MODES_ * W_; i += 256){
    int m = i >> 6, w = i & 63;
    float s, c; sincospif((float)((m * w) & 63) * (1.f / 32.f), &s, &c);
    tab[m][w][0] = c; tab[m][w][1] = -s;
  }
  __syncthreads();
  const int b = blockIdx.x >> 6, h = blockIdx.x & 63;
  const float* xr = x + ((size_t)b * HW_ + (size_t)h * W_) * C_;
  float ar[MODES_][3], ai[MODES_][3];
  #pragma unroll
  for (int m = 0; m < MODES_; ++m){
    #pragma unroll
    for (int j = 0; j < 3; ++j){ ar[m][j] = 0.f; ai[m][j] = 0.f; }
  }
  for (int w = 0; w < W_; ++w){
    float xv0 = xr[(size_t)w * C_ + tid];
    float xv1 = xr[(size_t)w * C_ + tid + 256];
    float xv2 = xr[(size_t)w * C_ + tid + 512];
    #pragma unroll
    for (int m = 0; m < MODES_; ++m){
      float c = tab[m][w][0], s = tab[m][w][1];
      ar[m][0] += xv0 * c; ai[m][0] += xv0 * s;
      ar[m][1] += xv1 * c; ai[m][1] += xv1 * s;
      ar[m][2] += xv2 * c; ai[m][2] += xv2 * s;
    }
  }
  float* Sp = S + ((size_t)(b * H_ + h) * (MODES_ * 2)) * C_;
  #pragma unroll
  for (int m = 0; m < MODES_; ++m){
    #pragma unroll
    for (int j = 0; j < 3; ++j){
      Sp[(size_t)(m * 2 + 0) * C_ + tid + j * 256] = ar[m][j];
      Sp[(size_t)(m * 2 + 1) * C_ + tid + j * 256] = ai[m][j];
    }
  }
}

// ---- MFMA block mixing, in place on S (r6 verbatim)
__global__ __launch_bounds__(256) void k_mix2(float* __restrict__ T,
    const unsigned short* __restrict__ Wp, const float* __restrict__ bb,
    const float* __restrict__ gates){
  __shared__ __align__(16) unsigned short sA[16 * SPA];
  const int tid = threadIdx.x;
  float* Tg = T + (size_t)blockIdx.x * 16 * C_;
  #pragma unroll
  for (int r = 0; r < 16; ++r){
    #pragma unroll
    for (int j = 0; j < 3; ++j){
      const int c = tid + 256 * j;
      sA[r * SPA + c] = f2bf(Tg[(size_t)r * C_ + c]);
    }
  }
  __syncthreads();
  const int wv = tid >> 6, ln = tid & 63;
  f32x4 acc[2][6];
  #pragma unroll
  for (int i = 0; i < 2; ++i)
    #pragma unroll
    for (int j = 0; j < 6; ++j) acc[i][j] = {0.f, 0.f, 0.f, 0.f};
  #pragma unroll
  for (int nn = 0; nn < 2; ++nn){
    const int n = wv * 2 + nn, col0 = n * BS_;
    #pragma unroll
    for (int ks = 0; ks < 3; ++ks){
      bf16x8 af = *(const bf16x8*)(sA + (ln & 15) * SPA + col0 + ks * 32 + (ln >> 4) * 8);
      #pragma unroll
      for (int ct = 0; ct < 6; ++ct){
        const unsigned short* bp = Wp + ((size_t)n * BS_ + ct * 16 + (ln & 15)) * BS_
                                      + ks * 32 + (ln >> 4) * 8;
        bf16x8 bf = *(const bf16x8*)bp;
        acc[nn][ct] = __builtin_amdgcn_mfma_f32_16x16x32_bf16(af, bf, acc[nn][ct], 0, 0, 0);
      }
    }
  }
  #pragma unroll
  for (int nn = 0; nn < 2; ++nn){
    const int n = wv * 2 + nn;
    const float g = 1.f / (1.f + expf(-gates[n]));
    #pragma unroll
    for (int ct = 0; ct < 6; ++ct){
      const int dcol = ct * 16 + (ln & 15);
      const int col = n * BS_ + dcol;
      const float gb = g * bb[n * BS_ + dcol];
      #pragma unroll
      for (int j = 0; j < 4; ++j){
        const int row = (ln >> 4) * 4 + j;               // C/D: col=lane&15, row=(lane>>4)*4+j
        const float wgt = (row < 2 ? 1.f : 2.f) * (1.f / 64.f);
        const size_t o = (size_t)row * C_ + col;
        Tg[o] = (acc[nn][ct][j] + gb - Tg[o]) * wgt;
      }
    }
  }
}

// ---- inverse W-DFT + residual add, emit x_out as bf16 (r1/r5/r6 verbatim)
__global__ __launch_bounds__(256) void k_inv_w(const float* __restrict__ Z, const float* __restrict__ x,
                                               unsigned short* __restrict__ xo){
  __shared__ float tab[W_][MODES_][2]; // cos, sin
  const int tid = threadIdx.x;
  for (int i = tid; i < W_ * MODES_; i += 256){
    int w = i >> 3, m = i & 7;
    float s, c; sincospif((float)((w * m) & 63) * (1.f / 32.f), &s, &c);
    tab[w][m][0] = c; tab[w][m][1] = s;
  }
  __syncthreads();
  const int b = blockIdx.x >> 6, h = blockIdx.x & 63;
  const float* Zp = Z + ((size_t)(b * H_ + h) * 16) * C_;
  float zr[MODES_][3], zi[MODES_][3];
  #pragma unroll
  for (int m = 0; m < MODES_; ++m){
    #pragma unroll
    for (int j = 0; j < 3; ++j){
      zr[m][j] = Zp[(size_t)(m * 2 + 0) * C_ + tid + j * 256];
      zi[m][j] = Zp[(size_t)(m * 2 + 1) * C_ + tid + j * 256];
    }
  }
  const float* xr = x + ((size_t)b * HW_ + (size_t)h * W_) * C_;
  unsigned short* xop = xo + ((size_t)b * HW_ + (size_t)h * W_) * C_;
  for (int w = 0; w < W_; ++w){
    float y0 = 0.f, y1 = 0.f, y2 = 0.f;
    #pragma unroll
    for (int m = 0; m < MODES_; ++m){
      float cw = tab[w][m][0], sw = tab[w][m][1];
      y0 += zr[m][0] * cw - zi[m][0] * sw;
      y1 += zr[m][1] * cw - zi[m][1] * sw;
      y2 += zr[m][2] * cw - zi[m][2] * sw;
    }
    size_t o = (size_t)w * C_;
    xop[o + tid]       = f2bf(xr[o + tid] + y0);
    xop[o + tid + 256] = f2bf(xr[o + tid + 256] + y1);
    xop[o + tid + 512] = f2bf(xr[o + tid + 512] + y2);
  }
}

// ---- projection GEMM: double-buffered, counted vmcnt, raw barriers (T4, r13).
__device__ __forceinline__ void async16(const void* g, const void* l){
  __builtin_amdgcn_global_load_lds((__attribute__((address_space(1))) void*)g,
                                   (__attribute__((address_space(3))) void*)l, 16, 0, 0);
}

__global__ __launch_bounds__(256) void k_gemm(const unsigned short* __restrict__ xo,
    const unsigned short* __restrict__ Wb, const float* __restrict__ b_out,
    const float* __restrict__ rescale, float* __restrict__ out){
  __shared__ __align__(16) unsigned short lA[2][128 * 64];
  __shared__ __align__(16) unsigned short lB[2][128 * 64];
  const int tid = threadIdx.x;
  const int wv = tid >> 6, ln = tid & 63;
  const int wg = (blockIdx.x & 7) * 384 + (blockIdx.x >> 3);   // XCD-aware bijective swizzle
  const int mt = wg / 6, nt = wg % 6;
  const int mbase = mt * 128, nbase = nt * 128;
  f32x4 acc[4][4];
  #pragma unroll
  for (int i = 0; i < 4; ++i)
    #pragma unroll
    for (int j = 0; j < 4; ++j) acc[i][j] = {0.f, 0.f, 0.f, 0.f};
  const int srow = ln >> 3;
  const int kb_lin = (ln & 7) << 4;

#define STAGE(pp, kt_) {                                                    \
    const int k0_ = (kt_) * 64;                                             \
    _Pragma("unroll")                                                       \
    for (int i_ = 0; i_ < 4; ++i_){                                         \
      const int ch_ = i_ * 4 + wv;                                          \
      const int row_ = ch_ * 8 + srow;                                      \
      const int kby_ = kb_lin ^ ((row_ & 7) << 4);                          \
      async16(xo + (size_t)(mbase + row_) * C_ + k0_ + (kby_ >> 1),         \
              ((const char*)lA[pp]) + ch_ * 1024);                          \
      async16(Wb + (size_t)(nbase + row_) * C_ + k0_ + (kby_ >> 1),         \
              ((const char*)lB[pp]) + ch_ * 1024);                          \
    } }
  // 8 loads/wave per STAGE. vmcnt discipline: wait only the CURRENT buffer's
  // 8 (oldest, in-order); the freshly-issued 8 stay in flight across s_barrier.
  STAGE(0, 0);
  asm volatile("s_waitcnt vmcnt(0)" ::: "memory");
  __builtin_amdgcn_s_barrier();
  __builtin_amdgcn_sched_barrier(0);
  for (int kt = 0; kt < 12; ++kt){
    const int p = kt & 1;
    if (kt + 1 < 12){
      STAGE(p ^ 1, kt + 1);                          // buf p^1: last read at kt-1, fenced below
      asm volatile("s_waitcnt vmcnt(8)" ::: "memory");   // cur buffer landed (per-wave)
    } else {
      asm volatile("s_waitcnt vmcnt(0)" ::: "memory");
    }
    __builtin_amdgcn_s_barrier();                    // all waves' cur loads visible
    __builtin_amdgcn_sched_barrier(0);
    const int wr = (wv >> 1) * 64, wc = (wv & 1) * 64;
    #pragma unroll
    for (int kk = 0; kk < 2; ++kk){
      bf16x8 af[4], bg[4];
      #pragma unroll
      for (int mi = 0; mi < 4; ++mi){
        const int row = wr + mi * 16 + (ln & 15);
        int off = (row << 7) + (kk << 6) + ((ln >> 4) << 4);
        off ^= (row & 7) << 4;                       // swizzled read
        af[mi] = *(const bf16x8*)(((const char*)lA[p]) + off);
      }
      #pragma unroll
      for (int ni = 0; ni < 4; ++ni){
        const int row = wc + ni * 16 + (ln & 15);
        int off = (row << 7) + (kk << 6) + ((ln >> 4) << 4);
        off ^= (row & 7) << 4;
        bg[ni] = *(const bf16x8*)(((const char*)lB[p]) + off);
      }
      #pragma unroll
      for (int mi = 0; mi < 4; ++mi){
        #pragma unroll
        for (int ni = 0; ni < 4; ++ni)
          acc[mi][ni] = __builtin_amdgcn_mfma_f32_16x16x32_bf16(af[mi], bg[ni], acc[mi][ni], 0, 0, 0);
      }
    }
    __builtin_amdgcn_sched_barrier(0);
    __builtin_amdgcn_s_barrier();                    // cur reads done before kt+1 overwrites
    __builtin_amdgcn_sched_barrier(0);
  }
#undef STAGE
  const float rs = *rescale;
  const int wr = (wv >> 1) * 64, wc = (wv & 1) * 64;
  #pragma unroll
  for (int mi = 0; mi < 4; ++mi){
    const int r0 = mbase + wr + mi * 16 + ((ln >> 4) << 2);
    #pragma unroll
    for (int ni = 0; ni < 4; ++ni){
      const int cidx = nbase + wc + ni * 16 + (ln & 15);
      const float bo = rs * b_out[cidx];
      #pragma unroll
      for (int j = 0; j < 4; ++j){
        const size_t o = (size_t)(r0 + j) * C_ + cidx;
        out[o] = bf2f(xo[o]) + rs * acc[mi][ni][j] + bo;  // C/D: col=lane&15, row=(lane>>4)*4+j
      }
    }
  }
}

extern "C" void kernel_launch(void* const* d_in, const int* in_sizes, int n_in,
                              void* d_out, int out_size, void* d_ws, size_t ws_size,
                              hipStream_t stream){
  const float* x       = (const float*)d_in[0];
  const float* bW      = (const float*)d_in[1];
  const float* bb      = (const float*)d_in[2];
  const float* gates   = (const float*)d_in[3];
  const float* W_out   = (const float*)d_in[4];
  const float* b_out   = (const float*)d_in[5];
  const float* rescale = (const float*)d_in[6];
  float* out = (float*)d_out;
  char* ws = (char*)d_ws;
  // ws layout (bytes): S 50331648 | xo bf16 100663296 | Wb bf16 1179648 | Wp bf16 147456
  float* S = (float*)(ws);
  unsigned short* xo = (unsigned short*)(ws + 50331648);
  unsigned short* Wb = (unsigned short*)(ws + 50331648 + 100663296);
  unsigned short* Wp = (unsigned short*)(ws + 50331648 + 100663296 + 1179648);

  k_cvt_prep<<<2312, 256, 0, stream>>>(W_out, Wb, bW, gates, Wp);
  k_fwd_w<<<B_ * H_, 256, 0, stream>>>(x, S);
  k_mix2<<<B_ * H_, 256, 0, stream>>>(S, Wp, bb, gates);   // MFMA mix, h-domain, in place
  k_inv_w<<<B_ * H_, 256, 0, stream>>>(S, x, xo);
  k_gemm<<<(HW_ * B_ / 128) * (C_ / 128), 256, 0, stream>>>(xo, Wb, b_out, rescale, out);
}